// Round 11
// baseline (227.645 us; speedup 1.0000x reference)
//
#include <hip/hip_runtime.h>
#include <hip/hip_bf16.h>
#include <math.h>

#define N_NODES 100000
#define N_EDGES 1600000
#define D_IN 64
#define D_HID 64
#define D_OUT 40
#define NBUCK 256
#define BSZ 391                 // nodes per bucket; 256*391 = 100096 >= N
#define BCAP 8192               // per-bucket capacity (mean ~7620 padded, 6+ sd margin)
#define P3_EPB 4096             // edges per k_place block
#define P3_GRID ((N_EDGES + P3_EPB - 1) / P3_EPB)   // 391
#define GEMM_GRID ((N_NODES + 63) / 64)             // 1563 blocks, 16 nodes/wave
#define AGG_GRID (N_NODES / 8)                      // 12500 blocks, 2 nodes/wave

typedef __hip_bfloat16 bf16;
typedef __attribute__((ext_vector_type(8))) short short8;
typedef __attribute__((ext_vector_type(4))) float f32x4;
typedef __attribute__((ext_vector_type(2))) _Float16 h2f;
typedef __attribute__((ext_vector_type(2))) __fp16 fp16x2;   // builtin return type

// fp32 -> bf16 bits, round-to-nearest-even (finite inputs)
__device__ __forceinline__ unsigned short f2b(float f) {
    union { float f; unsigned int u; } c; c.f = f;
    unsigned int u = c.u + 0x7FFFu + ((c.u >> 16) & 1u);
    return (unsigned short)(u >> 16);
}
// pack 2 fp32 -> 2 fp16 in one word
__device__ __forceinline__ unsigned int pkh(float a, float b) {
#if __has_builtin(__builtin_amdgcn_cvt_pkrtz)
    union { fp16x2 h; unsigned int u; } c;
    c.h = __builtin_amdgcn_cvt_pkrtz(a, b);
    return c.u;
#else
    union { _Float16 h[2]; unsigned int u; } c;
    c.h[0] = (_Float16)a; c.h[1] = (_Float16)b; return c.u;
#endif
}
// accumulate packed fp16 pair into two f32 accumulators (1 VALU/element via dot2)
__device__ __forceinline__ void acc2(unsigned int w, float& e, float& o) {
    union { unsigned int u; h2f h; } c; c.u = w;
#if __has_builtin(__builtin_amdgcn_fdot2)
    e = __builtin_amdgcn_fdot2(c.h, (h2f){(_Float16)1.f, (_Float16)0.f}, e, false);
    o = __builtin_amdgcn_fdot2(c.h, (h2f){(_Float16)0.f, (_Float16)1.f}, o, false);
#else
    e += (float)c.h[0]; o += (float)c.h[1];
#endif
}

// ---- zero ints ----
__global__ __launch_bounds__(256) void k_zero(int* __restrict__ p, int n) {
    int i = blockIdx.x * 256 + threadIdx.x;
    if (i < n) p[i] = 0;
}

// ---- place: single pass; part[] uses fixed per-bucket regions [b*BCAP ...).
__global__ __launch_bounds__(256) void k_place(const int* __restrict__ ei,
                                               int* __restrict__ fill_p,
                                               int* __restrict__ part) {
    __shared__ int cnt_l[NBUCK];
    __shared__ int base_l[NBUCK];
    cnt_l[threadIdx.x] = 0;
    __syncthreads();
    int e0 = blockIdx.x * P3_EPB;
    unsigned int meta[16];                     // (b<<21)|(lc<<12)|slot
#pragma unroll
    for (int k = 0; k < 16; k++) {
        int e = e0 + k * 256 + threadIdx.x;
        if (e < N_EDGES) {
            unsigned int c = (unsigned int)ei[N_EDGES + e];
            unsigned int b = c / 391u;
            unsigned int lc = c - b * 391u;
            unsigned int slot = atomicAdd(&cnt_l[b], 1);   // slot < 4096
            meta[k] = (b << 21) | (lc << 12) | slot;
        } else meta[k] = 0xFFFFFFFFu;
    }
    __syncthreads();
    int cv = cnt_l[threadIdx.x];
    if (cv) base_l[threadIdx.x] = threadIdx.x * BCAP +
                                  atomicAdd(&fill_p[threadIdx.x * 16], cv);
    __syncthreads();
#pragma unroll
    for (int k = 0; k < 16; k++) {
        if (meta[k] != 0xFFFFFFFFu) {
            int e = e0 + k * 256 + threadIdx.x;
            unsigned int b = meta[k] >> 21;
            unsigned int lc = (meta[k] >> 12) & 0x1FFu;
            unsigned int slot = meta[k] & 0xFFFu;
            unsigned int r = (unsigned int)ei[e];
            part[base_l[b] + slot] = (int)((lc << 17) | r);
        }
    }
}

// ---- build: per-bucket PADDED CSR + start/nkv/dinv ----
// Node lists padded to multiple of 8 with sentinel N_NODES (zero message row).
__global__ __launch_bounds__(256) void k_build(const int* __restrict__ part,
                                               const int* __restrict__ fill_p,
                                               int* __restrict__ start,
                                               int* __restrict__ nkv,
                                               float* __restrict__ dinv,
                                               int* __restrict__ csr) {
    __shared__ int deg_l[392];
    __shared__ int excl_l[392];        // exclusive scan of PADDED degrees
    int tid = threadIdx.x;
    int b = blockIdx.x;
    int m = fill_p[b * 16];            // edges in bucket
    int base = b * BCAP;               // part & csr region base
    for (int i = tid; i < 392; i += 256) deg_l[i] = 0;
    __syncthreads();
    for (int i = tid; i < m; i += 256)
        atomicAdd(&deg_l[(unsigned int)part[base + i] >> 17], 1);
    __syncthreads();
    // wave 0: exclusive scan of padded degrees
    if (tid < 64) {
        int carry = 0;
        for (int ch = 0; ch < 7; ch++) {       // 7*64 = 448 >= 392
            int idx = ch * 64 + tid;
            int val = (idx < 392) ? ((deg_l[idx] + 7) & ~7) : 0;
            int incl = val;
#pragma unroll
            for (int off = 1; off < 64; off <<= 1) {
                int u = __shfl_up(incl, off, 64);
                if (tid >= off) incl += u;
            }
            if (idx < 392) excl_l[idx] = carry + incl - val;
            carry += __shfl(incl, 63, 64);
        }
    }
    __syncthreads();
    int v0 = b * BSZ;
    for (int vl = tid; vl < BSZ; vl += 256) {
        int v = v0 + vl;
        if (v < N_NODES) {
            int d = deg_l[vl];
            start[v] = base + excl_l[vl];
            nkv[v] = (d + 7) >> 3;
            dinv[v] = rsqrtf((float)d + 1.0f);
        }
    }
    __syncthreads();
    // fill pad slots with zero-row sentinel (uses TRUE deg, before reuse)
    for (int j = tid; j < 392 * 8; j += 256) {
        int vl = j >> 3, sl = j & 7;
        int d = deg_l[vl];
        int pc = ((d + 7) & ~7) - d;           // 0..7 pad slots
        if (sl < pc) csr[base + excl_l[vl] + d + sl] = N_NODES;
    }
    __syncthreads();
    for (int i = tid; i < 392; i += 256) deg_l[i] = 0;   // reuse as fill
    __syncthreads();
    for (int i = tid; i < m; i += 256) {
        unsigned int p = (unsigned int)part[base + i];
        unsigned int lc = p >> 17;
        int s = atomicAdd(&deg_l[lc], 1);
        csr[base + excl_l[lc] + s] = (int)(p & 0x1FFFFu);
    }
}

// ---- prep: pack W1/W2 into bf16 MFMA A-fragments; zero sentinel fp16 rows ----
__global__ __launch_bounds__(256) void k_prep(const float* __restrict__ W1,
                                              const float* __restrict__ W2,
                                              unsigned short* __restrict__ wp1,
                                              unsigned short* __restrict__ wp2,
                                              unsigned int* __restrict__ gbh,
                                              unsigned int* __restrict__ g2h) {
    int tid = threadIdx.x;
    if (tid < 32) gbh[(size_t)N_NODES * 32 + tid] = 0;      // 128B zero row
    else if (tid < 52) g2h[(size_t)N_NODES * 20 + (tid - 32)] = 0;  // 80B zero row
    for (int i = tid; i < 4096; i += 256) {           // 2 kk * 4 jt * 64 lane * 8 e
        int e = i & 7, lane = (i >> 3) & 63, t = i >> 9;
        int kk = t >> 2, jt = t & 3;
        int row = kk * 32 + (lane >> 4) * 8 + e;
        int col = jt * 16 + (lane & 15);
        wp1[i] = f2b(W1[row * 64 + col]);
    }
    for (int i = tid; i < 3072; i += 256) {           // 2 kk * 3 jt * 64 lane * 8 e
        int e = i & 7, lane = (i >> 3) & 63, t = i >> 9;
        int kk = t / 3, jt = t - kk * 3;
        int row = kk * 32 + (lane >> 4) * 8 + e;
        int col = jt * 16 + (lane & 15);
        wp2[i] = (col < 40) ? f2b(W2[row * 40 + col]) : (unsigned short)0;
    }
}

// ---- layer1 GEMM via MFMA, fp16 row output (128B rows) ----
__global__ __launch_bounds__(256) void k_gemm1m(const float* __restrict__ x,
                                                const short8* __restrict__ wp,
                                                const float* __restrict__ dinv,
                                                unsigned short* __restrict__ gbh) {
    int lane = threadIdx.x & 63;
    int wid = threadIdx.x >> 6;
    int node0 = (blockIdx.x * 4 + wid) * 16;
    if (node0 >= N_NODES) return;
    int vr = node0 + (lane & 15);
    if (vr >= N_NODES) vr = N_NODES - 1;               // defensive (unreachable)
    int kg = lane >> 4;
    const float* px = x + (size_t)vr * 64 + kg * 8;
    short8 b0, b1;
    {
        float4 f0 = *(const float4*)px;
        float4 f1 = *(const float4*)(px + 4);
        b0[0] = (short)f2b(f0.x); b0[1] = (short)f2b(f0.y);
        b0[2] = (short)f2b(f0.z); b0[3] = (short)f2b(f0.w);
        b0[4] = (short)f2b(f1.x); b0[5] = (short)f2b(f1.y);
        b0[6] = (short)f2b(f1.z); b0[7] = (short)f2b(f1.w);
        float4 g0 = *(const float4*)(px + 32);
        float4 g1 = *(const float4*)(px + 36);
        b1[0] = (short)f2b(g0.x); b1[1] = (short)f2b(g0.y);
        b1[2] = (short)f2b(g0.z); b1[3] = (short)f2b(g0.w);
        b1[4] = (short)f2b(g1.x); b1[5] = (short)f2b(g1.y);
        b1[6] = (short)f2b(g1.z); b1[7] = (short)f2b(g1.w);
    }
    f32x4 acc[4];
#pragma unroll
    for (int jt = 0; jt < 4; jt++) acc[jt] = (f32x4){0.f, 0.f, 0.f, 0.f};
#pragma unroll
    for (int jt = 0; jt < 4; jt++) {
        acc[jt] = __builtin_amdgcn_mfma_f32_16x16x32_bf16(
            wp[(0 * 4 + jt) * 64 + lane], b0, acc[jt], 0, 0, 0);
        acc[jt] = __builtin_amdgcn_mfma_f32_16x16x32_bf16(
            wp[(1 * 4 + jt) * 64 + lane], b1, acc[jt], 0, 0, 0);
    }
    float d = dinv[vr];
    unsigned short* gp = gbh + (size_t)vr * 64 + kg * 4;
#pragma unroll
    for (int jt = 0; jt < 4; jt++) {
        uint2 w;
        w.x = pkh(acc[jt][0] * d, acc[jt][1] * d);
        w.y = pkh(acc[jt][2] * d, acc[jt][3] * d);
        *(uint2*)(gp + jt * 16) = w;
    }
}

// ---- layer2 GEMM via MFMA, fp16 row output (80B rows, 40 cols) ----
__global__ __launch_bounds__(256) void k_gemm2m(const unsigned short* __restrict__ hb,
                                                const short8* __restrict__ wp,
                                                const float* __restrict__ dinv,
                                                unsigned short* __restrict__ g2h) {
    int lane = threadIdx.x & 63;
    int wid = threadIdx.x >> 6;
    int node0 = (blockIdx.x * 4 + wid) * 16;
    if (node0 >= N_NODES) return;
    int vr = node0 + (lane & 15);
    if (vr >= N_NODES) vr = N_NODES - 1;
    int kg = lane >> 4;
    const short8* h8 = (const short8*)hb;
    short8 b0 = h8[(size_t)vr * 8 + kg];
    short8 b1 = h8[(size_t)vr * 8 + 4 + kg];
    f32x4 acc[3];
#pragma unroll
    for (int jt = 0; jt < 3; jt++) acc[jt] = (f32x4){0.f, 0.f, 0.f, 0.f};
#pragma unroll
    for (int jt = 0; jt < 3; jt++) {
        acc[jt] = __builtin_amdgcn_mfma_f32_16x16x32_bf16(
            wp[(0 * 3 + jt) * 64 + lane], b0, acc[jt], 0, 0, 0);
        acc[jt] = __builtin_amdgcn_mfma_f32_16x16x32_bf16(
            wp[(1 * 3 + jt) * 64 + lane], b1, acc[jt], 0, 0, 0);
    }
    float d = dinv[vr];
    unsigned short* gp = g2h + (size_t)vr * 40;
#pragma unroll
    for (int jt = 0; jt < 2; jt++) {
        uint2 w;
        w.x = pkh(acc[jt][0] * d, acc[jt][1] * d);
        w.y = pkh(acc[jt][2] * d, acc[jt][3] * d);
        *(uint2*)(gp + jt * 16 + kg * 4) = w;
    }
    if (kg < 2) {                                      // cols 32..39
        uint2 w;
        w.x = pkh(acc[2][0] * d, acc[2][1] * d);
        w.y = pkh(acc[2][2] * d, acc[2][3] * d);
        *(uint2*)(gp + 32 + kg * 4) = w;
    }
}

// ---- agg1: TWO nodes per wave, 8-lane groups, fp16 rows (128B), fdot2,
//      4-deep software pipeline (8 gathers in flight); zero-padded csr;
//      bias+ReLU -> hb ----
__global__ __launch_bounds__(256) void k_agg1(const int* __restrict__ csr,
                                              const int* __restrict__ start,
                                              const int* __restrict__ nkv,
                                              const unsigned int* __restrict__ gbh,
                                              const float* __restrict__ dinv,
                                              const float* __restrict__ b1,
                                              unsigned short* __restrict__ hb) {
    int lane = threadIdx.x & 63;
    int g = lane >> 3;          // 8 edge-groups of 8 lanes
    int lq = lane & 7;          // 16B slice lq (cols 8lq..8lq+7)
    int v0 = (blockIdx.x * 4 + (threadIdx.x >> 6)) * 2;
    int v1 = v0 + 1;
    int s0 = start[v0] + g, s1 = start[v1] + g;
    int n0 = nkv[v0], n1 = nkv[v1];
    float a0=0.f,a1=0.f,a2=0.f,a3=0.f,a4=0.f,a5=0.f,a6=0.f,a7=0.f;
    float c0=0.f,c1=0.f,c2=0.f,c3=0.f,c4=0.f,c5=0.f,c6=0.f,c7=0.f;
    if (g == 0) {               // self-loops for both nodes
        uint4 uA = *(const uint4*)(gbh + (size_t)v0 * 32 + lq * 4);
        acc2(uA.x, a0, a1); acc2(uA.y, a2, a3);
        acc2(uA.z, a4, a5); acc2(uA.w, a6, a7);
        uint4 uB = *(const uint4*)(gbh + (size_t)v1 * 32 + lq * 4);
        acc2(uB.x, c0, c1); acc2(uB.y, c2, c3);
        acc2(uB.z, c4, c5); acc2(uB.w, c6, c7);
    }
    int nc = (n0 < n1) ? n0 : n1;
    int nc4 = nc & ~3;
    for (int k = 0; k < nc4; k += 4) {   // 8 independent gathers in flight
        int rA0 = csr[s0 + (k + 0) * 8], rA1 = csr[s0 + (k + 1) * 8];
        int rA2 = csr[s0 + (k + 2) * 8], rA3 = csr[s0 + (k + 3) * 8];
        int rB0 = csr[s1 + (k + 0) * 8], rB1 = csr[s1 + (k + 1) * 8];
        int rB2 = csr[s1 + (k + 2) * 8], rB3 = csr[s1 + (k + 3) * 8];
        uint4 uA0 = *(const uint4*)(gbh + (size_t)rA0 * 32 + lq * 4);
        uint4 uA1 = *(const uint4*)(gbh + (size_t)rA1 * 32 + lq * 4);
        uint4 uA2 = *(const uint4*)(gbh + (size_t)rA2 * 32 + lq * 4);
        uint4 uA3 = *(const uint4*)(gbh + (size_t)rA3 * 32 + lq * 4);
        uint4 uB0 = *(const uint4*)(gbh + (size_t)rB0 * 32 + lq * 4);
        uint4 uB1 = *(const uint4*)(gbh + (size_t)rB1 * 32 + lq * 4);
        uint4 uB2 = *(const uint4*)(gbh + (size_t)rB2 * 32 + lq * 4);
        uint4 uB3 = *(const uint4*)(gbh + (size_t)rB3 * 32 + lq * 4);
        acc2(uA0.x, a0, a1); acc2(uA0.y, a2, a3);
        acc2(uA0.z, a4, a5); acc2(uA0.w, a6, a7);
        acc2(uA1.x, a0, a1); acc2(uA1.y, a2, a3);
        acc2(uA1.z, a4, a5); acc2(uA1.w, a6, a7);
        acc2(uA2.x, a0, a1); acc2(uA2.y, a2, a3);
        acc2(uA2.z, a4, a5); acc2(uA2.w, a6, a7);
        acc2(uA3.x, a0, a1); acc2(uA3.y, a2, a3);
        acc2(uA3.z, a4, a5); acc2(uA3.w, a6, a7);
        acc2(uB0.x, c0, c1); acc2(uB0.y, c2, c3);
        acc2(uB0.z, c4, c5); acc2(uB0.w, c6, c7);
        acc2(uB1.x, c0, c1); acc2(uB1.y, c2, c3);
        acc2(uB1.z, c4, c5); acc2(uB1.w, c6, c7);
        acc2(uB2.x, c0, c1); acc2(uB2.y, c2, c3);
        acc2(uB2.z, c4, c5); acc2(uB2.w, c6, c7);
        acc2(uB3.x, c0, c1); acc2(uB3.y, c2, c3);
        acc2(uB3.z, c4, c5); acc2(uB3.w, c6, c7);
    }
    for (int k = nc4; k < nc; k++) {
        int r0 = csr[s0 + k * 8];
        int r1 = csr[s1 + k * 8];
        uint4 uA = *(const uint4*)(gbh + (size_t)r0 * 32 + lq * 4);
        uint4 uB = *(const uint4*)(gbh + (size_t)r1 * 32 + lq * 4);
        acc2(uA.x, a0, a1); acc2(uA.y, a2, a3);
        acc2(uA.z, a4, a5); acc2(uA.w, a6, a7);
        acc2(uB.x, c0, c1); acc2(uB.y, c2, c3);
        acc2(uB.z, c4, c5); acc2(uB.w, c6, c7);
    }
    for (int k = nc; k < n0; k++) {    // tail node0 (wave-uniform)
        int r = csr[s0 + k * 8];
        uint4 u = *(const uint4*)(gbh + (size_t)r * 32 + lq * 4);
        acc2(u.x, a0, a1); acc2(u.y, a2, a3);
        acc2(u.z, a4, a5); acc2(u.w, a6, a7);
    }
    for (int k = nc; k < n1; k++) {    // tail node1 (wave-uniform)
        int r = csr[s1 + k * 8];
        uint4 u = *(const uint4*)(gbh + (size_t)r * 32 + lq * 4);
        acc2(u.x, c0, c1); acc2(u.y, c2, c3);
        acc2(u.z, c4, c5); acc2(u.w, c6, c7);
    }
    // fold the 8 edge-groups for both nodes (all 64 lanes active)
#pragma unroll
    for (int o = 8; o < 64; o <<= 1) {
        a0 += __shfl_xor(a0, o, 64); a1 += __shfl_xor(a1, o, 64);
        a2 += __shfl_xor(a2, o, 64); a3 += __shfl_xor(a3, o, 64);
        a4 += __shfl_xor(a4, o, 64); a5 += __shfl_xor(a5, o, 64);
        a6 += __shfl_xor(a6, o, 64); a7 += __shfl_xor(a7, o, 64);
        c0 += __shfl_xor(c0, o, 64); c1 += __shfl_xor(c1, o, 64);
        c2 += __shfl_xor(c2, o, 64); c3 += __shfl_xor(c3, o, 64);
        c4 += __shfl_xor(c4, o, 64); c5 += __shfl_xor(c5, o, 64);
        c6 += __shfl_xor(c6, o, 64); c7 += __shfl_xor(c7, o, 64);
    }
    // lanes 0-31 finish node0, lanes 32-63 finish node1
    bool hi = (lane >= 32);
    int v = hi ? v1 : v0;
    float d = dinv[v];
    float e0 = hi ? c0 : a0, e1 = hi ? c1 : a1, e2 = hi ? c2 : a2;
    float e3 = hi ? c3 : a3, e4 = hi ? c4 : a4, e5 = hi ? c5 : a5;
    float e6 = hi ? c6 : a6, e7 = hi ? c7 : a7;
    float4 bb0 = ((const float4*)b1)[lq * 2];
    float4 bb1 = ((const float4*)b1)[lq * 2 + 1];
    float h0 = fmaxf(d * e0 + bb0.x, 0.f), h1 = fmaxf(d * e1 + bb0.y, 0.f);
    float h2 = fmaxf(d * e2 + bb0.z, 0.f), h3 = fmaxf(d * e3 + bb0.w, 0.f);
    float h4 = fmaxf(d * e4 + bb1.x, 0.f), h5 = fmaxf(d * e5 + bb1.y, 0.f);
    float h6 = fmaxf(d * e6 + bb1.z, 0.f), h7 = fmaxf(d * e7 + bb1.w, 0.f);
    if (g == 0 || g == 4) {            // g==0 -> v0 (lo half), g==4 -> v1 (hi half)
        uint4 o;
        o.x = (unsigned int)f2b(h0) | ((unsigned int)f2b(h1) << 16);
        o.y = (unsigned int)f2b(h2) | ((unsigned int)f2b(h3) << 16);
        o.z = (unsigned int)f2b(h4) | ((unsigned int)f2b(h5) << 16);
        o.w = (unsigned int)f2b(h6) | ((unsigned int)f2b(h7) << 16);
        *(uint4*)(hb + (size_t)v * 64 + lq * 8) = o;
    }
}

// ---- agg2: TWO nodes per wave, fp16 rows (80B, 5 active slices), fdot2,
//      4-deep software pipeline; zero-padded csr; bias + log_softmax -> out ----
__global__ __launch_bounds__(256) void k_agg2(const int* __restrict__ csr,
                                              const int* __restrict__ start,
                                              const int* __restrict__ nkv,
                                              const unsigned int* __restrict__ g2h,
                                              const float* __restrict__ dinv,
                                              const float* __restrict__ b2v,
                                              float* __restrict__ out) {
    int lane = threadIdx.x & 63;
    int g = lane >> 3;
    int lq = lane & 7;          // active slices lq<5 (5x16B = 80B row)
    int lqc = (lq < 5) ? lq : 0;   // idle lanes alias slice 0
    int v0 = (blockIdx.x * 4 + (threadIdx.x >> 6)) * 2;
    int v1 = v0 + 1;
    int s0 = start[v0] + g, s1 = start[v1] + g;
    int n0 = nkv[v0], n1 = nkv[v1];
    float a0=0.f,a1=0.f,a2=0.f,a3=0.f,a4=0.f,a5=0.f,a6=0.f,a7=0.f;
    float c0=0.f,c1=0.f,c2=0.f,c3=0.f,c4=0.f,c5=0.f,c6=0.f,c7=0.f;
    if (g == 0) {               // self-loops (idle lanes accumulate slice0 junk,
        uint4 uA = *(const uint4*)(g2h + (size_t)v0 * 20 + lqc * 4);  // masked later)
        acc2(uA.x, a0, a1); acc2(uA.y, a2, a3);
        acc2(uA.z, a4, a5); acc2(uA.w, a6, a7);
        uint4 uB = *(const uint4*)(g2h + (size_t)v1 * 20 + lqc * 4);
        acc2(uB.x, c0, c1); acc2(uB.y, c2, c3);
        acc2(uB.z, c4, c5); acc2(uB.w, c6, c7);
    }
    int nc = (n0 < n1) ? n0 : n1;
    int nc4 = nc & ~3;
    for (int k = 0; k < nc4; k += 4) {   // 8 independent gathers in flight
        int rA0 = csr[s0 + (k + 0) * 8], rA1 = csr[s0 + (k + 1) * 8];
        int rA2 = csr[s0 + (k + 2) * 8], rA3 = csr[s0 + (k + 3) * 8];
        int rB0 = csr[s1 + (k + 0) * 8], rB1 = csr[s1 + (k + 1) * 8];
        int rB2 = csr[s1 + (k + 2) * 8], rB3 = csr[s1 + (k + 3) * 8];
        uint4 uA0 = *(const uint4*)(g2h + (size_t)rA0 * 20 + lqc * 4);
        uint4 uA1 = *(const uint4*)(g2h + (size_t)rA1 * 20 + lqc * 4);
        uint4 uA2 = *(const uint4*)(g2h + (size_t)rA2 * 20 + lqc * 4);
        uint4 uA3 = *(const uint4*)(g2h + (size_t)rA3 * 20 + lqc * 4);
        uint4 uB0 = *(const uint4*)(g2h + (size_t)rB0 * 20 + lqc * 4);
        uint4 uB1 = *(const uint4*)(g2h + (size_t)rB1 * 20 + lqc * 4);
        uint4 uB2 = *(const uint4*)(g2h + (size_t)rB2 * 20 + lqc * 4);
        uint4 uB3 = *(const uint4*)(g2h + (size_t)rB3 * 20 + lqc * 4);
        acc2(uA0.x, a0, a1); acc2(uA0.y, a2, a3);
        acc2(uA0.z, a4, a5); acc2(uA0.w, a6, a7);
        acc2(uA1.x, a0, a1); acc2(uA1.y, a2, a3);
        acc2(uA1.z, a4, a5); acc2(uA1.w, a6, a7);
        acc2(uA2.x, a0, a1); acc2(uA2.y, a2, a3);
        acc2(uA2.z, a4, a5); acc2(uA2.w, a6, a7);
        acc2(uA3.x, a0, a1); acc2(uA3.y, a2, a3);
        acc2(uA3.z, a4, a5); acc2(uA3.w, a6, a7);
        acc2(uB0.x, c0, c1); acc2(uB0.y, c2, c3);
        acc2(uB0.z, c4, c5); acc2(uB0.w, c6, c7);
        acc2(uB1.x, c0, c1); acc2(uB1.y, c2, c3);
        acc2(uB1.z, c4, c5); acc2(uB1.w, c6, c7);
        acc2(uB2.x, c0, c1); acc2(uB2.y, c2, c3);
        acc2(uB2.z, c4, c5); acc2(uB2.w, c6, c7);
        acc2(uB3.x, c0, c1); acc2(uB3.y, c2, c3);
        acc2(uB3.z, c4, c5); acc2(uB3.w, c6, c7);
    }
    for (int k = nc4; k < nc; k++) {
        int r0 = csr[s0 + k * 8];
        int r1 = csr[s1 + k * 8];
        uint4 uA = *(const uint4*)(g2h + (size_t)r0 * 20 + lqc * 4);
        uint4 uB = *(const uint4*)(g2h + (size_t)r1 * 20 + lqc * 4);
        acc2(uA.x, a0, a1); acc2(uA.y, a2, a3);
        acc2(uA.z, a4, a5); acc2(uA.w, a6, a7);
        acc2(uB.x, c0, c1); acc2(uB.y, c2, c3);
        acc2(uB.z, c4, c5); acc2(uB.w, c6, c7);
    }
    for (int k = nc; k < n0; k++) {
        int r = csr[s0 + k * 8];
        uint4 u = *(const uint4*)(g2h + (size_t)r * 20 + lqc * 4);
        acc2(u.x, a0, a1); acc2(u.y, a2, a3);
        acc2(u.z, a4, a5); acc2(u.w, a6, a7);
    }
    for (int k = nc; k < n1; k++) {
        int r = csr[s1 + k * 8];
        uint4 u = *(const uint4*)(g2h + (size_t)r * 20 + lqc * 4);
        acc2(u.x, c0, c1); acc2(u.y, c2, c3);
        acc2(u.z, c4, c5); acc2(u.w, c6, c7);
    }
#pragma unroll
    for (int o = 8; o < 64; o <<= 1) {
        a0 += __shfl_xor(a0, o, 64); a1 += __shfl_xor(a1, o, 64);
        a2 += __shfl_xor(a2, o, 64); a3 += __shfl_xor(a3, o, 64);
        a4 += __shfl_xor(a4, o, 64); a5 += __shfl_xor(a5, o, 64);
        a6 += __shfl_xor(a6, o, 64); a7 += __shfl_xor(a7, o, 64);
        c0 += __shfl_xor(c0, o, 64); c1 += __shfl_xor(c1, o, 64);
        c2 += __shfl_xor(c2, o, 64); c3 += __shfl_xor(c3, o, 64);
        c4 += __shfl_xor(c4, o, 64); c5 += __shfl_xor(c5, o, 64);
        c6 += __shfl_xor(c6, o, 64); c7 += __shfl_xor(c7, o, 64);
    }
    // lanes 0-31 finish node0, lanes 32-63 finish node1
    bool hi = (lane >= 32);
    int v = hi ? v1 : v0;
    float d = dinv[v];
    float e0 = hi ? c0 : a0, e1 = hi ? c1 : a1, e2 = hi ? c2 : a2;
    float e3 = hi ? c3 : a3, e4 = hi ? c4 : a4, e5 = hi ? c5 : a5;
    float e6 = hi ? c6 : a6, e7 = hi ? c7 : a7;
    bool act = (lq < 5);
    float4 bb0 = act ? ((const float4*)b2v)[lq * 2] : make_float4(0.f,0.f,0.f,0.f);
    float4 bb1 = act ? ((const float4*)b2v)[lq * 2 + 1] : make_float4(0.f,0.f,0.f,0.f);
    float l0 = act ? d * e0 + bb0.x : -INFINITY;
    float l1 = act ? d * e1 + bb0.y : -INFINITY;
    float l2 = act ? d * e2 + bb0.z : -INFINITY;
    float l3 = act ? d * e3 + bb0.w : -INFINITY;
    float l4 = act ? d * e4 + bb1.x : -INFINITY;
    float l5 = act ? d * e5 + bb1.y : -INFINITY;
    float l6 = act ? d * e6 + bb1.z : -INFINITY;
    float l7 = act ? d * e7 + bb1.w : -INFINITY;
    float m = fmaxf(fmaxf(fmaxf(l0, l1), fmaxf(l2, l3)),
                    fmaxf(fmaxf(l4, l5), fmaxf(l6, l7)));
#pragma unroll
    for (int o = 1; o < 8; o <<= 1) m = fmaxf(m, __shfl_xor(m, o, 64));
    float ex = act ? (__expf(l0 - m) + __expf(l1 - m) + __expf(l2 - m) +
                      __expf(l3 - m) + __expf(l4 - m) + __expf(l5 - m) +
                      __expf(l6 - m) + __expf(l7 - m)) : 0.f;
#pragma unroll
    for (int o = 1; o < 8; o <<= 1) ex += __shfl_xor(ex, o, 64);
    float lse = m + logf(ex);
    if ((g == 0 || g == 4) && act) {   // g==0 -> v0, g==4 -> v1
        float* op = out + (size_t)v * 40 + lq * 8;
        *(float4*)op = make_float4(l0 - lse, l1 - lse, l2 - lse, l3 - lse);
        *(float4*)(op + 4) = make_float4(l4 - lse, l5 - lse, l6 - lse, l7 - lse);
    }
}

extern "C" void kernel_launch(void* const* d_in, const int* in_sizes, int n_in,
                              void* d_out, int out_size, void* d_ws, size_t ws_size,
                              hipStream_t stream) {
    const float* x  = (const float*)d_in[0];
    const int*   ei = (const int*)d_in[1];
    const float* W1 = (const float*)d_in[2];
    const float* b1 = (const float*)d_in[3];
    const float* W2 = (const float*)d_in[4];
    const float* b2 = (const float*)d_in[5];
    float* out = (float*)d_out;

    const int N = N_NODES;
    // Workspace layout (ints from base), total ~51 MB:
    int*   part  = (int*)d_ws;                  // 256*BCAP bucketized edges
    int*   csr   = part + NBUCK * BCAP;         // 256*BCAP padded CSR
    int*   start = csr + NBUCK * BCAP;          // N
    int*   nkv   = start + N;                   // N  (padded deg / 8)
    int*   fill  = nkv + N;                     // 256*16 padded counters
    float* dinv  = (float*)(fill + 4096);       // N
    unsigned short* hb  = (unsigned short*)(dinv + N);        // N*64 bf16
    unsigned short* gbh = hb + (size_t)N * 64;                // (N+1)*64 fp16
    unsigned short* g2h = gbh + (size_t)(N + 1) * 64;         // (N+1)*40 fp16
    unsigned short* wp1 = g2h + (size_t)(N + 1) * 40;         // 4096 bf16 W1 frags
    unsigned short* wp2 = wp1 + 4096;                         // 3072 bf16 W2 frags

    k_zero<<<16, 256, 0, stream>>>(fill, 4096);
    k_prep<<<1, 256, 0, stream>>>(W1, W2, wp1, wp2,
                                  (unsigned int*)gbh, (unsigned int*)g2h);
    k_place<<<P3_GRID, 256, 0, stream>>>(ei, fill, part);
    k_build<<<NBUCK, 256, 0, stream>>>(part, fill, start, nkv, dinv, csr);
    k_gemm1m<<<GEMM_GRID, 256, 0, stream>>>(x, (const short8*)wp1, dinv, gbh);
    k_agg1<<<AGG_GRID, 256, 0, stream>>>(csr, start, nkv, (const unsigned int*)gbh,
                                         dinv, b1, hb);
    k_gemm2m<<<GEMM_GRID, 256, 0, stream>>>(hb, (const short8*)wp2, dinv, g2h);
    k_agg2<<<AGG_GRID, 256, 0, stream>>>(csr, start, nkv, (const unsigned int*)g2h,
                                         dinv, b2, out);
}

// Round 12
// 215.575 us; speedup vs baseline: 1.0560x; 1.0560x over previous
//
#include <hip/hip_runtime.h>
#include <hip/hip_bf16.h>
#include <math.h>

#define N_NODES 100000
#define N_EDGES 1600000
#define D_IN 64
#define D_HID 64
#define D_OUT 40
#define NBUCK 256
#define BSZ 391                 // nodes per bucket; 256*391 = 100096 >= N
#define BCAP 8192               // per-bucket capacity (mean ~7620 padded, 6+ sd margin)
#define P3_EPB 4096             // edges per k_place block
#define P3_GRID ((N_EDGES + P3_EPB - 1) / P3_EPB)   // 391
#define GEMM_GRID ((N_NODES + 63) / 64)             // 1563 blocks, 16 nodes/wave
#define AGG_GRID (N_NODES / 8)                      // 12500 blocks, 2 nodes/wave

typedef __hip_bfloat16 bf16;
typedef __attribute__((ext_vector_type(8))) short short8;
typedef __attribute__((ext_vector_type(4))) float f32x4;
typedef __attribute__((ext_vector_type(2))) _Float16 h2f;
typedef __attribute__((ext_vector_type(2))) __fp16 fp16x2;   // builtin return type

// fp32 -> bf16 bits, round-to-nearest-even (finite inputs)
__device__ __forceinline__ unsigned short f2b(float f) {
    union { float f; unsigned int u; } c; c.f = f;
    unsigned int u = c.u + 0x7FFFu + ((c.u >> 16) & 1u);
    return (unsigned short)(u >> 16);
}
// pack 2 fp32 -> 2 fp16 in one word
__device__ __forceinline__ unsigned int pkh(float a, float b) {
#if __has_builtin(__builtin_amdgcn_cvt_pkrtz)
    union { fp16x2 h; unsigned int u; } c;
    c.h = __builtin_amdgcn_cvt_pkrtz(a, b);
    return c.u;
#else
    union { _Float16 h[2]; unsigned int u; } c;
    c.h[0] = (_Float16)a; c.h[1] = (_Float16)b; return c.u;
#endif
}
// accumulate packed fp16 pair into two f32 accumulators (1 VALU/element via dot2)
__device__ __forceinline__ void acc2(unsigned int w, float& e, float& o) {
    union { unsigned int u; h2f h; } c; c.u = w;
#if __has_builtin(__builtin_amdgcn_fdot2)
    e = __builtin_amdgcn_fdot2(c.h, (h2f){(_Float16)1.f, (_Float16)0.f}, e, false);
    o = __builtin_amdgcn_fdot2(c.h, (h2f){(_Float16)0.f, (_Float16)1.f}, o, false);
#else
    e += (float)c.h[0]; o += (float)c.h[1];
#endif
}

// ---- zero ints ----
__global__ __launch_bounds__(256) void k_zero(int* __restrict__ p, int n) {
    int i = blockIdx.x * 256 + threadIdx.x;
    if (i < n) p[i] = 0;
}

// ---- place: single pass; part[] uses fixed per-bucket regions [b*BCAP ...).
__global__ __launch_bounds__(256) void k_place(const int* __restrict__ ei,
                                               int* __restrict__ fill_p,
                                               int* __restrict__ part) {
    __shared__ int cnt_l[NBUCK];
    __shared__ int base_l[NBUCK];
    cnt_l[threadIdx.x] = 0;
    __syncthreads();
    int e0 = blockIdx.x * P3_EPB;
    unsigned int meta[16];                     // (b<<21)|(lc<<12)|slot
#pragma unroll
    for (int k = 0; k < 16; k++) {
        int e = e0 + k * 256 + threadIdx.x;
        if (e < N_EDGES) {
            unsigned int c = (unsigned int)ei[N_EDGES + e];
            unsigned int b = c / 391u;
            unsigned int lc = c - b * 391u;
            unsigned int slot = atomicAdd(&cnt_l[b], 1);   // slot < 4096
            meta[k] = (b << 21) | (lc << 12) | slot;
        } else meta[k] = 0xFFFFFFFFu;
    }
    __syncthreads();
    int cv = cnt_l[threadIdx.x];
    if (cv) base_l[threadIdx.x] = threadIdx.x * BCAP +
                                  atomicAdd(&fill_p[threadIdx.x * 16], cv);
    __syncthreads();
#pragma unroll
    for (int k = 0; k < 16; k++) {
        if (meta[k] != 0xFFFFFFFFu) {
            int e = e0 + k * 256 + threadIdx.x;
            unsigned int b = meta[k] >> 21;
            unsigned int lc = (meta[k] >> 12) & 0x1FFu;
            unsigned int slot = meta[k] & 0xFFFu;
            unsigned int r = (unsigned int)ei[e];
            part[base_l[b] + slot] = (int)((lc << 17) | r);
        }
    }
}

// ---- build: per-bucket PADDED CSR + start/nkv/dinv ----
// Node lists padded to multiple of 8 with sentinel N_NODES (zero message row).
__global__ __launch_bounds__(256) void k_build(const int* __restrict__ part,
                                               const int* __restrict__ fill_p,
                                               int* __restrict__ start,
                                               int* __restrict__ nkv,
                                               float* __restrict__ dinv,
                                               int* __restrict__ csr) {
    __shared__ int deg_l[392];
    __shared__ int excl_l[392];        // exclusive scan of PADDED degrees
    int tid = threadIdx.x;
    int b = blockIdx.x;
    int m = fill_p[b * 16];            // edges in bucket
    int base = b * BCAP;               // part & csr region base
    for (int i = tid; i < 392; i += 256) deg_l[i] = 0;
    __syncthreads();
    for (int i = tid; i < m; i += 256)
        atomicAdd(&deg_l[(unsigned int)part[base + i] >> 17], 1);
    __syncthreads();
    // wave 0: exclusive scan of padded degrees
    if (tid < 64) {
        int carry = 0;
        for (int ch = 0; ch < 7; ch++) {       // 7*64 = 448 >= 392
            int idx = ch * 64 + tid;
            int val = (idx < 392) ? ((deg_l[idx] + 7) & ~7) : 0;
            int incl = val;
#pragma unroll
            for (int off = 1; off < 64; off <<= 1) {
                int u = __shfl_up(incl, off, 64);
                if (tid >= off) incl += u;
            }
            if (idx < 392) excl_l[idx] = carry + incl - val;
            carry += __shfl(incl, 63, 64);
        }
    }
    __syncthreads();
    int v0 = b * BSZ;
    for (int vl = tid; vl < BSZ; vl += 256) {
        int v = v0 + vl;
        if (v < N_NODES) {
            int d = deg_l[vl];
            start[v] = base + excl_l[vl];
            nkv[v] = (d + 7) >> 3;
            dinv[v] = rsqrtf((float)d + 1.0f);
        }
    }
    __syncthreads();
    // fill pad slots with zero-row sentinel (uses TRUE deg, before reuse)
    for (int j = tid; j < 392 * 8; j += 256) {
        int vl = j >> 3, sl = j & 7;
        int d = deg_l[vl];
        int pc = ((d + 7) & ~7) - d;           // 0..7 pad slots
        if (sl < pc) csr[base + excl_l[vl] + d + sl] = N_NODES;
    }
    __syncthreads();
    for (int i = tid; i < 392; i += 256) deg_l[i] = 0;   // reuse as fill
    __syncthreads();
    for (int i = tid; i < m; i += 256) {
        unsigned int p = (unsigned int)part[base + i];
        unsigned int lc = p >> 17;
        int s = atomicAdd(&deg_l[lc], 1);
        csr[base + excl_l[lc] + s] = (int)(p & 0x1FFFFu);
    }
}

// ---- prep: pack W1/W2 into bf16 MFMA A-fragments; zero sentinel fp16 rows ----
__global__ __launch_bounds__(256) void k_prep(const float* __restrict__ W1,
                                              const float* __restrict__ W2,
                                              unsigned short* __restrict__ wp1,
                                              unsigned short* __restrict__ wp2,
                                              unsigned int* __restrict__ gbh,
                                              unsigned int* __restrict__ g2h) {
    int tid = threadIdx.x;
    if (tid < 32) gbh[(size_t)N_NODES * 32 + tid] = 0;      // 128B zero row
    else if (tid < 52) g2h[(size_t)N_NODES * 20 + (tid - 32)] = 0;  // 80B zero row
    for (int i = tid; i < 4096; i += 256) {           // 2 kk * 4 jt * 64 lane * 8 e
        int e = i & 7, lane = (i >> 3) & 63, t = i >> 9;
        int kk = t >> 2, jt = t & 3;
        int row = kk * 32 + (lane >> 4) * 8 + e;
        int col = jt * 16 + (lane & 15);
        wp1[i] = f2b(W1[row * 64 + col]);
    }
    for (int i = tid; i < 3072; i += 256) {           // 2 kk * 3 jt * 64 lane * 8 e
        int e = i & 7, lane = (i >> 3) & 63, t = i >> 9;
        int kk = t / 3, jt = t - kk * 3;
        int row = kk * 32 + (lane >> 4) * 8 + e;
        int col = jt * 16 + (lane & 15);
        wp2[i] = (col < 40) ? f2b(W2[row * 40 + col]) : (unsigned short)0;
    }
}

// ---- layer1 GEMM via MFMA, fp16 row output (128B rows) ----
__global__ __launch_bounds__(256) void k_gemm1m(const float* __restrict__ x,
                                                const short8* __restrict__ wp,
                                                const float* __restrict__ dinv,
                                                unsigned short* __restrict__ gbh) {
    int lane = threadIdx.x & 63;
    int wid = threadIdx.x >> 6;
    int node0 = (blockIdx.x * 4 + wid) * 16;
    if (node0 >= N_NODES) return;
    int vr = node0 + (lane & 15);
    if (vr >= N_NODES) vr = N_NODES - 1;               // defensive (unreachable)
    int kg = lane >> 4;
    const float* px = x + (size_t)vr * 64 + kg * 8;
    short8 b0, b1;
    {
        float4 f0 = *(const float4*)px;
        float4 f1 = *(const float4*)(px + 4);
        b0[0] = (short)f2b(f0.x); b0[1] = (short)f2b(f0.y);
        b0[2] = (short)f2b(f0.z); b0[3] = (short)f2b(f0.w);
        b0[4] = (short)f2b(f1.x); b0[5] = (short)f2b(f1.y);
        b0[6] = (short)f2b(f1.z); b0[7] = (short)f2b(f1.w);
        float4 g0 = *(const float4*)(px + 32);
        float4 g1 = *(const float4*)(px + 36);
        b1[0] = (short)f2b(g0.x); b1[1] = (short)f2b(g0.y);
        b1[2] = (short)f2b(g0.z); b1[3] = (short)f2b(g0.w);
        b1[4] = (short)f2b(g1.x); b1[5] = (short)f2b(g1.y);
        b1[6] = (short)f2b(g1.z); b1[7] = (short)f2b(g1.w);
    }
    f32x4 acc[4];
#pragma unroll
    for (int jt = 0; jt < 4; jt++) acc[jt] = (f32x4){0.f, 0.f, 0.f, 0.f};
#pragma unroll
    for (int jt = 0; jt < 4; jt++) {
        acc[jt] = __builtin_amdgcn_mfma_f32_16x16x32_bf16(
            wp[(0 * 4 + jt) * 64 + lane], b0, acc[jt], 0, 0, 0);
        acc[jt] = __builtin_amdgcn_mfma_f32_16x16x32_bf16(
            wp[(1 * 4 + jt) * 64 + lane], b1, acc[jt], 0, 0, 0);
    }
    float d = dinv[vr];
    unsigned short* gp = gbh + (size_t)vr * 64 + kg * 4;
#pragma unroll
    for (int jt = 0; jt < 4; jt++) {
        uint2 w;
        w.x = pkh(acc[jt][0] * d, acc[jt][1] * d);
        w.y = pkh(acc[jt][2] * d, acc[jt][3] * d);
        *(uint2*)(gp + jt * 16) = w;
    }
}

// ---- layer2 GEMM via MFMA, fp16 row output (80B rows, 40 cols) ----
__global__ __launch_bounds__(256) void k_gemm2m(const unsigned short* __restrict__ hb,
                                                const short8* __restrict__ wp,
                                                const float* __restrict__ dinv,
                                                unsigned short* __restrict__ g2h) {
    int lane = threadIdx.x & 63;
    int wid = threadIdx.x >> 6;
    int node0 = (blockIdx.x * 4 + wid) * 16;
    if (node0 >= N_NODES) return;
    int vr = node0 + (lane & 15);
    if (vr >= N_NODES) vr = N_NODES - 1;
    int kg = lane >> 4;
    const short8* h8 = (const short8*)hb;
    short8 b0 = h8[(size_t)vr * 8 + kg];
    short8 b1 = h8[(size_t)vr * 8 + 4 + kg];
    f32x4 acc[3];
#pragma unroll
    for (int jt = 0; jt < 3; jt++) acc[jt] = (f32x4){0.f, 0.f, 0.f, 0.f};
#pragma unroll
    for (int jt = 0; jt < 3; jt++) {
        acc[jt] = __builtin_amdgcn_mfma_f32_16x16x32_bf16(
            wp[(0 * 3 + jt) * 64 + lane], b0, acc[jt], 0, 0, 0);
        acc[jt] = __builtin_amdgcn_mfma_f32_16x16x32_bf16(
            wp[(1 * 3 + jt) * 64 + lane], b1, acc[jt], 0, 0, 0);
    }
    float d = dinv[vr];
    unsigned short* gp = g2h + (size_t)vr * 40;
#pragma unroll
    for (int jt = 0; jt < 2; jt++) {
        uint2 w;
        w.x = pkh(acc[jt][0] * d, acc[jt][1] * d);
        w.y = pkh(acc[jt][2] * d, acc[jt][3] * d);
        *(uint2*)(gp + jt * 16 + kg * 4) = w;
    }
    if (kg < 2) {                                      // cols 32..39
        uint2 w;
        w.x = pkh(acc[2][0] * d, acc[2][1] * d);
        w.y = pkh(acc[2][2] * d, acc[2][3] * d);
        *(uint2*)(gp + 32 + kg * 4) = w;
    }
}

// ---- agg1: TWO nodes per wave, 8-lane groups, fp16 rows (128B), fdot2
//      accumulate (1 VALU/elem, no scales); zero-padded csr; bias+ReLU -> hb ----
__global__ __launch_bounds__(256) void k_agg1(const int* __restrict__ csr,
                                              const int* __restrict__ start,
                                              const int* __restrict__ nkv,
                                              const unsigned int* __restrict__ gbh,
                                              const float* __restrict__ dinv,
                                              const float* __restrict__ b1,
                                              unsigned short* __restrict__ hb) {
    int lane = threadIdx.x & 63;
    int g = lane >> 3;          // 8 edge-groups of 8 lanes
    int lq = lane & 7;          // 16B slice lq (cols 8lq..8lq+7)
    int v0 = (blockIdx.x * 4 + (threadIdx.x >> 6)) * 2;
    int v1 = v0 + 1;
    int s0 = start[v0] + g, s1 = start[v1] + g;
    int n0 = nkv[v0], n1 = nkv[v1];
    float a0=0.f,a1=0.f,a2=0.f,a3=0.f,a4=0.f,a5=0.f,a6=0.f,a7=0.f;
    float c0=0.f,c1=0.f,c2=0.f,c3=0.f,c4=0.f,c5=0.f,c6=0.f,c7=0.f;
    if (g == 0) {               // self-loops for both nodes
        uint4 uA = *(const uint4*)(gbh + (size_t)v0 * 32 + lq * 4);
        acc2(uA.x, a0, a1); acc2(uA.y, a2, a3);
        acc2(uA.z, a4, a5); acc2(uA.w, a6, a7);
        uint4 uB = *(const uint4*)(gbh + (size_t)v1 * 32 + lq * 4);
        acc2(uB.x, c0, c1); acc2(uB.y, c2, c3);
        acc2(uB.z, c4, c5); acc2(uB.w, c6, c7);
    }
    int nc = (n0 < n1) ? n0 : n1;
#pragma unroll 2
    for (int k = 0; k < nc; k++) {     // both chains in flight
        int r0 = csr[s0 + k * 8];
        int r1 = csr[s1 + k * 8];
        uint4 uA = *(const uint4*)(gbh + (size_t)r0 * 32 + lq * 4);
        uint4 uB = *(const uint4*)(gbh + (size_t)r1 * 32 + lq * 4);
        acc2(uA.x, a0, a1); acc2(uA.y, a2, a3);
        acc2(uA.z, a4, a5); acc2(uA.w, a6, a7);
        acc2(uB.x, c0, c1); acc2(uB.y, c2, c3);
        acc2(uB.z, c4, c5); acc2(uB.w, c6, c7);
    }
    for (int k = nc; k < n0; k++) {    // tail node0 (wave-uniform)
        int r = csr[s0 + k * 8];
        uint4 u = *(const uint4*)(gbh + (size_t)r * 32 + lq * 4);
        acc2(u.x, a0, a1); acc2(u.y, a2, a3);
        acc2(u.z, a4, a5); acc2(u.w, a6, a7);
    }
    for (int k = nc; k < n1; k++) {    // tail node1 (wave-uniform)
        int r = csr[s1 + k * 8];
        uint4 u = *(const uint4*)(gbh + (size_t)r * 32 + lq * 4);
        acc2(u.x, c0, c1); acc2(u.y, c2, c3);
        acc2(u.z, c4, c5); acc2(u.w, c6, c7);
    }
    // fold the 8 edge-groups for both nodes (all 64 lanes active)
#pragma unroll
    for (int o = 8; o < 64; o <<= 1) {
        a0 += __shfl_xor(a0, o, 64); a1 += __shfl_xor(a1, o, 64);
        a2 += __shfl_xor(a2, o, 64); a3 += __shfl_xor(a3, o, 64);
        a4 += __shfl_xor(a4, o, 64); a5 += __shfl_xor(a5, o, 64);
        a6 += __shfl_xor(a6, o, 64); a7 += __shfl_xor(a7, o, 64);
        c0 += __shfl_xor(c0, o, 64); c1 += __shfl_xor(c1, o, 64);
        c2 += __shfl_xor(c2, o, 64); c3 += __shfl_xor(c3, o, 64);
        c4 += __shfl_xor(c4, o, 64); c5 += __shfl_xor(c5, o, 64);
        c6 += __shfl_xor(c6, o, 64); c7 += __shfl_xor(c7, o, 64);
    }
    // lanes 0-31 finish node0, lanes 32-63 finish node1
    bool hi = (lane >= 32);
    int v = hi ? v1 : v0;
    float d = dinv[v];
    float e0 = hi ? c0 : a0, e1 = hi ? c1 : a1, e2 = hi ? c2 : a2;
    float e3 = hi ? c3 : a3, e4 = hi ? c4 : a4, e5 = hi ? c5 : a5;
    float e6 = hi ? c6 : a6, e7 = hi ? c7 : a7;
    float4 bb0 = ((const float4*)b1)[lq * 2];
    float4 bb1 = ((const float4*)b1)[lq * 2 + 1];
    float h0 = fmaxf(d * e0 + bb0.x, 0.f), h1 = fmaxf(d * e1 + bb0.y, 0.f);
    float h2 = fmaxf(d * e2 + bb0.z, 0.f), h3 = fmaxf(d * e3 + bb0.w, 0.f);
    float h4 = fmaxf(d * e4 + bb1.x, 0.f), h5 = fmaxf(d * e5 + bb1.y, 0.f);
    float h6 = fmaxf(d * e6 + bb1.z, 0.f), h7 = fmaxf(d * e7 + bb1.w, 0.f);
    if (g == 0 || g == 4) {            // g==0 -> v0 (lo half), g==4 -> v1 (hi half)
        uint4 o;
        o.x = (unsigned int)f2b(h0) | ((unsigned int)f2b(h1) << 16);
        o.y = (unsigned int)f2b(h2) | ((unsigned int)f2b(h3) << 16);
        o.z = (unsigned int)f2b(h4) | ((unsigned int)f2b(h5) << 16);
        o.w = (unsigned int)f2b(h6) | ((unsigned int)f2b(h7) << 16);
        *(uint4*)(hb + (size_t)v * 64 + lq * 8) = o;
    }
}

// ---- agg2: TWO nodes per wave, fp16 rows (80B, 5 active slices), fdot2;
//      zero-padded csr; fused bias + log_softmax -> out ----
__global__ __launch_bounds__(256) void k_agg2(const int* __restrict__ csr,
                                              const int* __restrict__ start,
                                              const int* __restrict__ nkv,
                                              const unsigned int* __restrict__ g2h,
                                              const float* __restrict__ dinv,
                                              const float* __restrict__ b2v,
                                              float* __restrict__ out) {
    int lane = threadIdx.x & 63;
    int g = lane >> 3;
    int lq = lane & 7;          // active slices lq<5 (5x16B = 80B row)
    int lqc = (lq < 5) ? lq : 0;   // idle lanes alias slice 0
    int v0 = (blockIdx.x * 4 + (threadIdx.x >> 6)) * 2;
    int v1 = v0 + 1;
    int s0 = start[v0] + g, s1 = start[v1] + g;
    int n0 = nkv[v0], n1 = nkv[v1];
    float a0=0.f,a1=0.f,a2=0.f,a3=0.f,a4=0.f,a5=0.f,a6=0.f,a7=0.f;
    float c0=0.f,c1=0.f,c2=0.f,c3=0.f,c4=0.f,c5=0.f,c6=0.f,c7=0.f;
    if (g == 0) {               // self-loops (idle lanes accumulate slice0 junk,
        uint4 uA = *(const uint4*)(g2h + (size_t)v0 * 20 + lqc * 4);  // masked later)
        acc2(uA.x, a0, a1); acc2(uA.y, a2, a3);
        acc2(uA.z, a4, a5); acc2(uA.w, a6, a7);
        uint4 uB = *(const uint4*)(g2h + (size_t)v1 * 20 + lqc * 4);
        acc2(uB.x, c0, c1); acc2(uB.y, c2, c3);
        acc2(uB.z, c4, c5); acc2(uB.w, c6, c7);
    }
    int nc = (n0 < n1) ? n0 : n1;
#pragma unroll 2
    for (int k = 0; k < nc; k++) {
        int r0 = csr[s0 + k * 8];
        int r1 = csr[s1 + k * 8];
        uint4 uA = *(const uint4*)(g2h + (size_t)r0 * 20 + lqc * 4);
        uint4 uB = *(const uint4*)(g2h + (size_t)r1 * 20 + lqc * 4);
        acc2(uA.x, a0, a1); acc2(uA.y, a2, a3);
        acc2(uA.z, a4, a5); acc2(uA.w, a6, a7);
        acc2(uB.x, c0, c1); acc2(uB.y, c2, c3);
        acc2(uB.z, c4, c5); acc2(uB.w, c6, c7);
    }
    for (int k = nc; k < n0; k++) {
        int r = csr[s0 + k * 8];
        uint4 u = *(const uint4*)(g2h + (size_t)r * 20 + lqc * 4);
        acc2(u.x, a0, a1); acc2(u.y, a2, a3);
        acc2(u.z, a4, a5); acc2(u.w, a6, a7);
    }
    for (int k = nc; k < n1; k++) {
        int r = csr[s1 + k * 8];
        uint4 u = *(const uint4*)(g2h + (size_t)r * 20 + lqc * 4);
        acc2(u.x, c0, c1); acc2(u.y, c2, c3);
        acc2(u.z, c4, c5); acc2(u.w, c6, c7);
    }
#pragma unroll
    for (int o = 8; o < 64; o <<= 1) {
        a0 += __shfl_xor(a0, o, 64); a1 += __shfl_xor(a1, o, 64);
        a2 += __shfl_xor(a2, o, 64); a3 += __shfl_xor(a3, o, 64);
        a4 += __shfl_xor(a4, o, 64); a5 += __shfl_xor(a5, o, 64);
        a6 += __shfl_xor(a6, o, 64); a7 += __shfl_xor(a7, o, 64);
        c0 += __shfl_xor(c0, o, 64); c1 += __shfl_xor(c1, o, 64);
        c2 += __shfl_xor(c2, o, 64); c3 += __shfl_xor(c3, o, 64);
        c4 += __shfl_xor(c4, o, 64); c5 += __shfl_xor(c5, o, 64);
        c6 += __shfl_xor(c6, o, 64); c7 += __shfl_xor(c7, o, 64);
    }
    // lanes 0-31 finish node0, lanes 32-63 finish node1
    bool hi = (lane >= 32);
    int v = hi ? v1 : v0;
    float d = dinv[v];
    float e0 = hi ? c0 : a0, e1 = hi ? c1 : a1, e2 = hi ? c2 : a2;
    float e3 = hi ? c3 : a3, e4 = hi ? c4 : a4, e5 = hi ? c5 : a5;
    float e6 = hi ? c6 : a6, e7 = hi ? c7 : a7;
    bool act = (lq < 5);
    float4 bb0 = act ? ((const float4*)b2v)[lq * 2] : make_float4(0.f,0.f,0.f,0.f);
    float4 bb1 = act ? ((const float4*)b2v)[lq * 2 + 1] : make_float4(0.f,0.f,0.f,0.f);
    float l0 = act ? d * e0 + bb0.x : -INFINITY;
    float l1 = act ? d * e1 + bb0.y : -INFINITY;
    float l2 = act ? d * e2 + bb0.z : -INFINITY;
    float l3 = act ? d * e3 + bb0.w : -INFINITY;
    float l4 = act ? d * e4 + bb1.x : -INFINITY;
    float l5 = act ? d * e5 + bb1.y : -INFINITY;
    float l6 = act ? d * e6 + bb1.z : -INFINITY;
    float l7 = act ? d * e7 + bb1.w : -INFINITY;
    float m = fmaxf(fmaxf(fmaxf(l0, l1), fmaxf(l2, l3)),
                    fmaxf(fmaxf(l4, l5), fmaxf(l6, l7)));
#pragma unroll
    for (int o = 1; o < 8; o <<= 1) m = fmaxf(m, __shfl_xor(m, o, 64));
    float ex = act ? (__expf(l0 - m) + __expf(l1 - m) + __expf(l2 - m) +
                      __expf(l3 - m) + __expf(l4 - m) + __expf(l5 - m) +
                      __expf(l6 - m) + __expf(l7 - m)) : 0.f;
#pragma unroll
    for (int o = 1; o < 8; o <<= 1) ex += __shfl_xor(ex, o, 64);
    float lse = m + logf(ex);
    if ((g == 0 || g == 4) && act) {   // g==0 -> v0, g==4 -> v1
        float* op = out + (size_t)v * 40 + lq * 8;
        *(float4*)op = make_float4(l0 - lse, l1 - lse, l2 - lse, l3 - lse);
        *(float4*)(op + 4) = make_float4(l4 - lse, l5 - lse, l6 - lse, l7 - lse);
    }
}

extern "C" void kernel_launch(void* const* d_in, const int* in_sizes, int n_in,
                              void* d_out, int out_size, void* d_ws, size_t ws_size,
                              hipStream_t stream) {
    const float* x  = (const float*)d_in[0];
    const int*   ei = (const int*)d_in[1];
    const float* W1 = (const float*)d_in[2];
    const float* b1 = (const float*)d_in[3];
    const float* W2 = (const float*)d_in[4];
    const float* b2 = (const float*)d_in[5];
    float* out = (float*)d_out;

    const int N = N_NODES;
    // Workspace layout (ints from base), total ~51 MB:
    int*   part  = (int*)d_ws;                  // 256*BCAP bucketized edges
    int*   csr   = part + NBUCK * BCAP;         // 256*BCAP padded CSR
    int*   start = csr + NBUCK * BCAP;          // N
    int*   nkv   = start + N;                   // N  (padded deg / 8)
    int*   fill  = nkv + N;                     // 256*16 padded counters
    float* dinv  = (float*)(fill + 4096);       // N
    unsigned short* hb  = (unsigned short*)(dinv + N);        // N*64 bf16
    unsigned short* gbh = hb + (size_t)N * 64;                // (N+1)*64 fp16
    unsigned short* g2h = gbh + (size_t)(N + 1) * 64;         // (N+1)*40 fp16
    unsigned short* wp1 = g2h + (size_t)(N + 1) * 40;         // 4096 bf16 W1 frags
    unsigned short* wp2 = wp1 + 4096;                         // 3072 bf16 W2 frags

    k_zero<<<16, 256, 0, stream>>>(fill, 4096);
    k_prep<<<1, 256, 0, stream>>>(W1, W2, wp1, wp2,
                                  (unsigned int*)gbh, (unsigned int*)g2h);
    k_place<<<P3_GRID, 256, 0, stream>>>(ei, fill, part);
    k_build<<<NBUCK, 256, 0, stream>>>(part, fill, start, nkv, dinv, csr);
    k_gemm1m<<<GEMM_GRID, 256, 0, stream>>>(x, (const short8*)wp1, dinv, gbh);
    k_agg1<<<AGG_GRID, 256, 0, stream>>>(csr, start, nkv, (const unsigned int*)gbh,
                                         dinv, b1, hb);
    k_gemm2m<<<GEMM_GRID, 256, 0, stream>>>(hb, (const short8*)wp2, dinv, g2h);
    k_agg2<<<AGG_GRID, 256, 0, stream>>>(csr, start, nkv, (const unsigned int*)g2h,
                                         dinv, b2, out);
}